// Round 1
// baseline (646.291 us; speedup 1.0000x reference)
//
#include <hip/hip_runtime.h>
#include <cstdint>
#include <cstddef>

// Problem constants (match reference setup_inputs)
#define Bb   256
#define Tt   250
#define DIN  700
#define Hh   128
#define DOUT 20

// ---------------------------------------------------------------------------
// Phase 1: H1[b*T+t][h] = x[b][t][:] @ W1[:,h] + b1[h]
// M = 64000, K = 700, N = 128. Classic LDS-tiled f32 GEMM.
// BM=64, BN=128, BK=20 (700 = 35*20 exact). 256 threads, 4x8 micro-tile.
// ---------------------------------------------------------------------------
constexpr int BM = 64;
constexpr int BK = 20;
constexpr int BN = 128;

__global__ __launch_bounds__(256) void gemm_h1(const float* __restrict__ x,
                                               const float* __restrict__ W1,
                                               const float* __restrict__ b1,
                                               float* __restrict__ H1) {
    __shared__ float As[BM][BK];   // x tile, natural layout
    __shared__ float Bs[BK][BN];   // W1 tile

    const int tid = threadIdx.x;
    const int tx  = tid & 15;   // column group: cols tx*8 .. tx*8+7
    const int ty  = tid >> 4;   // row group:    rows ty*4 .. ty*4+3
    const int m0  = blockIdx.x * BM;

    float acc[4][8];
#pragma unroll
    for (int r = 0; r < 4; ++r)
#pragma unroll
        for (int c = 0; c < 8; ++c) acc[r][c] = 0.f;

    for (int k0 = 0; k0 < DIN; k0 += BK) {
        // Stage x tile: 64x20 = 1280 floats, 5 per thread
#pragma unroll
        for (int j = tid; j < BM * BK; j += 256) {
            int m = j / BK, k = j - m * BK;
            As[m][k] = x[(size_t)(m0 + m) * DIN + (k0 + k)];
        }
        // Stage W1 tile: 20x128 = 2560 floats, 10 per thread (coalesced)
#pragma unroll
        for (int j = tid; j < BK * BN; j += 256) {
            int k = j >> 7, n = j & 127;
            Bs[k][n] = W1[(size_t)(k0 + k) * BN + n];
        }
        __syncthreads();

#pragma unroll
        for (int kk = 0; kk < BK; ++kk) {
            float a[4], bv[8];
#pragma unroll
            for (int r = 0; r < 4; ++r) a[r] = As[ty * 4 + r][kk];
#pragma unroll
            for (int c = 0; c < 8; ++c) bv[c] = Bs[kk][tx * 8 + c];
#pragma unroll
            for (int r = 0; r < 4; ++r)
#pragma unroll
                for (int c = 0; c < 8; ++c)
                    acc[r][c] = fmaf(a[r], bv[c], acc[r][c]);
        }
        __syncthreads();
    }

#pragma unroll
    for (int r = 0; r < 4; ++r) {
        size_t row = (size_t)(m0 + ty * 4 + r);
#pragma unroll
        for (int c = 0; c < 8; ++c) {
            H1[row * Hh + tx * 8 + c] = acc[r][c] + b1[tx * 8 + c];
        }
    }
}

// ---------------------------------------------------------------------------
// Phase 2: the recurrence. One block per batch row (256 blocks), 128 threads
// = one thread per hidden unit. Spikes are binary -> y @ W is a sparse
// row-sum over the active-index list, built each step with ballot+popcount.
// Ascending-k summation == dense sequential dot bit-exactly (adding zeros
// is exact), so numerics stay in the f32-reorder noise class.
// ---------------------------------------------------------------------------
__global__ __launch_bounds__(128) void recurrent(
    const float* __restrict__ H1,   const float* __restrict__ rcW1,
    const float* __restrict__ rcb1, const float* __restrict__ W2,
    const float* __restrict__ b2,   const float* __restrict__ rcW2,
    const float* __restrict__ rcb2, const float* __restrict__ W3,
    const float* __restrict__ b3,   float* __restrict__ out) {

    const int b    = blockIdx.x;
    const int h    = threadIdx.x;       // 0..127
    const int lane = h & 63;
    const int wv   = h >> 6;            // wave 0/1

    __shared__ int list1[Hh];
    __shared__ int list2[Hh];
    __shared__ unsigned long long wmask[2];

    float v1 = 0.f, v2 = 0.f, accv = 0.f;
    int n1 = 0, n2 = 0;

    const float rcb1h = rcb1[h];
    const float bb2   = b2[h] + rcb2[h];
    const float b3h   = (h < DOUT) ? b3[h] : 0.f;
    const float* __restrict__ h1p = H1 + (size_t)b * Tt * Hh;

    for (int t = 0; t < Tt; ++t) {
        // ---- layer 1: u1 = h1 + rcb1 + sum_{k in A1} rcW1[k,:] ----
        float u1 = h1p[(size_t)t * Hh + h] + rcb1h;
        {
            int i = 0;
            for (; i + 4 <= n1; i += 4) {
                float a0 = rcW1[list1[i    ] * Hh + h];
                float a1 = rcW1[list1[i + 1] * Hh + h];
                float a2 = rcW1[list1[i + 2] * Hh + h];
                float a3 = rcW1[list1[i + 3] * Hh + h];
                u1 += a0; u1 += a1; u1 += a2; u1 += a3;
            }
            for (; i < n1; ++i) u1 += rcW1[list1[i] * Hh + h];
        }
        v1 = v1 + (u1 - v1) * 0.5f;          // exact /2
        const bool s1 = (v1 >= 1.0f);
        if (s1) v1 = 0.f;

        __syncthreads();                      // (a) list1/wmask consumed
        unsigned long long m1 = __ballot((int)s1);
        if (lane == 0) wmask[wv] = m1;
        __syncthreads();                      // (b)
        {
            int base = wv ? __popcll(wmask[0]) : 0;
            if (s1) list1[base + __popcll(m1 & ((1ull << lane) - 1ull))] = h;
            n1 = __popcll(wmask[0]) + __popcll(wmask[1]);
        }
        __syncthreads();                      // (c) list1 ready

        // ---- layer 2: u2 = b2+rcb2 + sum_{A1new} W2 + sum_{A2} rcW2 ----
        float u2 = bb2;
        {
            int i = 0;
            for (; i + 4 <= n1; i += 4) {
                float a0 = W2[list1[i    ] * Hh + h];
                float a1 = W2[list1[i + 1] * Hh + h];
                float a2 = W2[list1[i + 2] * Hh + h];
                float a3 = W2[list1[i + 3] * Hh + h];
                u2 += a0; u2 += a1; u2 += a2; u2 += a3;
            }
            for (; i < n1; ++i) u2 += W2[list1[i] * Hh + h];
        }
        {
            int i = 0;
            for (; i + 4 <= n2; i += 4) {
                float a0 = rcW2[list2[i    ] * Hh + h];
                float a1 = rcW2[list2[i + 1] * Hh + h];
                float a2 = rcW2[list2[i + 2] * Hh + h];
                float a3 = rcW2[list2[i + 3] * Hh + h];
                u2 += a0; u2 += a1; u2 += a2; u2 += a3;
            }
            for (; i < n2; ++i) u2 += rcW2[list2[i] * Hh + h];
        }
        v2 = v2 + (u2 - v2) * 0.5f;
        const bool s2 = (v2 >= 1.0f);
        if (s2) v2 = 0.f;

        __syncthreads();                      // (d) list2/wmask consumed
        unsigned long long m2 = __ballot((int)s2);
        if (lane == 0) wmask[wv] = m2;
        __syncthreads();                      // (e)
        {
            int base = wv ? __popcll(wmask[0]) : 0;
            if (s2) list2[base + __popcll(m2 & ((1ull << lane) - 1ull))] = h;
            n2 = __popcll(wmask[0]) + __popcll(wmask[1]);
        }
        __syncthreads();                      // (f) list2 ready

        // ---- readout: acc += y2 @ W3 + b3 ----
        if (h < DOUT) {
            float tmp = 0.f;
            for (int i = 0; i < n2; ++i) tmp += W3[list2[i] * DOUT + h];
            accv += tmp + b3h;
        }
    }

    if (h < DOUT) out[b * DOUT + h] = accv;
}

// ---------------------------------------------------------------------------
extern "C" void kernel_launch(void* const* d_in, const int* in_sizes, int n_in,
                              void* d_out, int out_size, void* d_ws, size_t ws_size,
                              hipStream_t stream) {
    const float* x    = (const float*)d_in[0];
    const float* W1   = (const float*)d_in[1];
    const float* b1   = (const float*)d_in[2];
    const float* rcW1 = (const float*)d_in[3];
    const float* rcb1 = (const float*)d_in[4];
    const float* W2   = (const float*)d_in[5];
    const float* b2   = (const float*)d_in[6];
    const float* rcW2 = (const float*)d_in[7];
    const float* rcb2 = (const float*)d_in[8];
    const float* W3   = (const float*)d_in[9];
    const float* b3   = (const float*)d_in[10];

    float* out = (float*)d_out;
    float* H1  = (float*)d_ws;   // 64000 x 128 f32 = 32.77 MB

    gemm_h1<<<(Bb * Tt) / BM, 256, 0, stream>>>(x, W1, b1, H1);
    recurrent<<<Bb, Hh, 0, stream>>>(H1, rcW1, rcb1, W2, b2, rcW2, rcb2, W3,
                                     b3, out);
}

// Round 2
// 574.100 us; speedup vs baseline: 1.1257x; 1.1257x over previous
//
#include <hip/hip_runtime.h>
#include <cstdint>
#include <cstddef>

// Problem constants (match reference setup_inputs)
#define Bb   256
#define Tt   250
#define DIN  700
#define Hh   128
#define DOUT 20

// ---------------------------------------------------------------------------
// Phase 1: H1[b*T+t][h] = x[b][t][:] @ W1[:,h] + b1[h]
// M=64000, K=700, N=128. 128x128 tile, BK=20 (700=35*20), 256 threads,
// 8x8 micro-tile (64 FMA per 4 ds_read_b128). A transposed in LDS so both
// operand reads are float4 (b128, 2-way bank alias = free).
// ---------------------------------------------------------------------------
constexpr int BM = 128;
constexpr int BK = 20;
constexpr int BN = 128;

__global__ __launch_bounds__(256, 2) void gemm_h1(const float* __restrict__ x,
                                                  const float* __restrict__ W1,
                                                  const float* __restrict__ b1,
                                                  float* __restrict__ H1) {
    __shared__ float Ast[BK][BM];   // x tile, TRANSPOSED: Ast[k][m]
    __shared__ float Bs[BK][BN];    // W1 tile, natural

    const int tid = threadIdx.x;
    const int tx  = tid & 15;       // col group: cols tx*8 .. +7
    const int ty  = tid >> 4;       // row group: rows ty*8 .. +7
    const int m0  = blockIdx.x * BM;

    float acc[8][8];
#pragma unroll
    for (int r = 0; r < 8; ++r)
#pragma unroll
        for (int c = 0; c < 8; ++c) acc[r][c] = 0.f;

    for (int k0 = 0; k0 < DIN; k0 += BK) {
        // Stage A: 128 rows x 20 k. 5 float4 per row = 640 float4.
        // row = idx/5 keeps global reads clustered (5 lanes share a row's 80B).
#pragma unroll
        for (int idx = tid; idx < 640; idx += 256) {
            int row = idx / 5;
            int kq  = (idx - row * 5) * 4;
            const float4 v =
                *(const float4*)&x[(size_t)(m0 + row) * DIN + (k0 + kq)];
            Ast[kq + 0][row] = v.x;
            Ast[kq + 1][row] = v.y;
            Ast[kq + 2][row] = v.z;
            Ast[kq + 3][row] = v.w;
        }
        // Stage B: 20 rows x 128 cols. 32 float4 per row = 640 float4.
#pragma unroll
        for (int idx = tid; idx < 640; idx += 256) {
            int kr = idx >> 5;
            int nq = (idx & 31) * 4;
            *(float4*)&Bs[kr][nq] =
                *(const float4*)&W1[(size_t)(k0 + kr) * BN + nq];
        }
        __syncthreads();

#pragma unroll
        for (int kk = 0; kk < BK; ++kk) {
            float a[8], bv[8];
            *(float4*)&a[0]  = *(const float4*)&Ast[kk][ty * 8];
            *(float4*)&a[4]  = *(const float4*)&Ast[kk][ty * 8 + 4];
            *(float4*)&bv[0] = *(const float4*)&Bs[kk][tx * 8];
            *(float4*)&bv[4] = *(const float4*)&Bs[kk][tx * 8 + 4];
#pragma unroll
            for (int r = 0; r < 8; ++r)
#pragma unroll
                for (int c = 0; c < 8; ++c)
                    acc[r][c] = fmaf(a[r], bv[c], acc[r][c]);
        }
        __syncthreads();
    }

    float bb[8];
#pragma unroll
    for (int c = 0; c < 8; ++c) bb[c] = b1[tx * 8 + c];

#pragma unroll
    for (int r = 0; r < 8; ++r) {
        size_t row = (size_t)(m0 + ty * 8 + r);
        float4 o0, o1;
        o0.x = acc[r][0] + bb[0]; o0.y = acc[r][1] + bb[1];
        o0.z = acc[r][2] + bb[2]; o0.w = acc[r][3] + bb[3];
        o1.x = acc[r][4] + bb[4]; o1.y = acc[r][5] + bb[5];
        o1.z = acc[r][6] + bb[6]; o1.w = acc[r][7] + bb[7];
        *(float4*)&H1[row * Hh + tx * 8]     = o0;
        *(float4*)&H1[row * Hh + tx * 8 + 4] = o1;
    }
}

// ---------------------------------------------------------------------------
// Phase 2: recurrence. 256 blocks (1/batch row) x 256 threads (2-way split-K
// over the sparse sums; state replicated across halves — bit-identical since
// both compute from the same LDS partials). rcW1+rcW2 staged in LDS (128 KB);
// W2 stays global (only short-window gather). h1 staged 8 steps at a time in
// LDS so per-step global loads don't stall every barrier's vmcnt(0) drain.
// Readout hoisted: sum_t(y2@W3+b3) == cnt2@W3 + T*b3 (spikes binary, W3
// const), so the T-loop only counts spikes.
// ---------------------------------------------------------------------------
__global__ __launch_bounds__(256, 1) void recurrent(
    const float* __restrict__ H1,   const float* __restrict__ rcW1,
    const float* __restrict__ rcb1, const float* __restrict__ W2,
    const float* __restrict__ b2,   const float* __restrict__ rcW2,
    const float* __restrict__ rcb2, const float* __restrict__ W3,
    const float* __restrict__ b3,   float* __restrict__ out) {

    __shared__ float sRc1[Hh * Hh];       // 64 KB
    __shared__ float sRc2[Hh * Hh];       // 64 KB
    __shared__ float sH1[8 * Hh];         // 4 KB: 8 timesteps of h1
    __shared__ int   list1[Hh];
    __shared__ int   list2[Hh];
    __shared__ unsigned long long wmask[2];
    __shared__ float sPart[2][Hh];

    const int tid  = threadIdx.x;
    const int h    = tid & 127;
    const int half = tid >> 7;            // 0 or 1
    const int lane = tid & 63;
    const int wid  = tid >> 6;            // wave 0..3
    const int b    = blockIdx.x;

    // ---- stage rcW1, rcW2 into LDS (coalesced float4) ----
#pragma unroll
    for (int i = tid * 4; i < Hh * Hh; i += 256 * 4) {
        *(float4*)&sRc1[i] = *(const float4*)&rcW1[i];
        *(float4*)&sRc2[i] = *(const float4*)&rcW2[i];
    }

    float v1 = 0.f, v2 = 0.f;
    int   cnt2 = 0;
    int   n1 = 0, n2 = 0;

    const float rcb1h = rcb1[h];
    const float bb2   = b2[h] + rcb2[h];
    const float* __restrict__ h1p = H1 + (size_t)b * Tt * Hh;

    __syncthreads();   // staging done (also orders first sH1 chunk below)

    for (int t = 0; t < Tt; ++t) {
        // ---- refill h1 chunk every 8 steps ----
        if ((t & 7) == 0) {
            int flat = t * Hh + tid * 4;
            float4 v = make_float4(0.f, 0.f, 0.f, 0.f);
            if (flat < Tt * Hh) v = *(const float4*)&h1p[flat];
            *(float4*)&sH1[tid * 4] = v;
        }

        // ---- layer 1 partial: my half of sum rcW1[k][h], k in list1 ----
        float u1p = 0.f;
        {
#pragma unroll 4
            for (int i = half; i < n1; i += 2)
                u1p += sRc1[list1[i] * Hh + h];
        }
        sPart[half][h] = u1p;
        __syncthreads();                  // (1) partials + h1 chunk ready

        float u1 = sH1[(t & 7) * Hh + h] + rcb1h + sPart[0][h] + sPart[1][h];
        v1 = v1 + (u1 - v1) * 0.5f;
        const bool s1 = (v1 >= 1.0f);
        if (s1) v1 = 0.f;

        unsigned long long m1 = __ballot((int)s1);
        if (lane == 0 && wid < 2) wmask[wid] = m1;
        __syncthreads();                  // (2) masks ready
        {
            unsigned long long M0 = wmask[0], M1 = wmask[1];
            if (half == 0 && s1) {
                int base = wid ? __popcll(M0) : 0;
                list1[base + __popcll(m1 & ((1ull << lane) - 1ull))] = h;
            }
            n1 = __popcll(M0) + __popcll(M1);
        }
        __syncthreads();                  // (3) list1 ready

        // ---- layer 2 partial: W2 (global) over list1 + rcW2 (LDS) list2 ----
        float q0 = 0.f, q1 = 0.f, q2 = 0.f, q3 = 0.f;
        {
            int i = half;
            for (; i + 6 < n1; i += 8) {
                float w0 = W2[list1[i]     * Hh + h];
                float w1 = W2[list1[i + 2] * Hh + h];
                float w2 = W2[list1[i + 4] * Hh + h];
                float w3 = W2[list1[i + 6] * Hh + h];
                q0 += w0; q1 += w1; q2 += w2; q3 += w3;
            }
            for (; i < n1; i += 2) q0 += W2[list1[i] * Hh + h];
        }
        float u2p = (q0 + q1) + (q2 + q3);
        {
#pragma unroll 4
            for (int i = half; i < n2; i += 2)
                u2p += sRc2[list2[i] * Hh + h];
        }
        sPart[half][h] = u2p;
        __syncthreads();                  // (4) partials ready

        float u2 = bb2 + sPart[0][h] + sPart[1][h];
        v2 = v2 + (u2 - v2) * 0.5f;
        const bool s2 = (v2 >= 1.0f);
        if (s2) v2 = 0.f;
        cnt2 += s2 ? 1 : 0;

        unsigned long long m2 = __ballot((int)s2);
        if (lane == 0 && wid < 2) wmask[wid] = m2;
        __syncthreads();                  // (5) masks ready
        {
            unsigned long long M0 = wmask[0], M1 = wmask[1];
            if (half == 0 && s2) {
                int base = wid ? __popcll(M0) : 0;
                list2[base + __popcll(m2 & ((1ull << lane) - 1ull))] = h;
            }
            n2 = __popcll(M0) + __popcll(M1);
        }
        // no barrier here: next consumer of list2 is after next step's (3)
    }

    // ---- readout: out[b] = cnt2 @ W3 + T*b3 ----
    __syncthreads();
    if (half == 0) sPart[0][h] = (float)cnt2;
    __syncthreads();
    if (tid < DOUT) {
        float o = (float)Tt * b3[tid];
#pragma unroll 4
        for (int k = 0; k < Hh; ++k) o += sPart[0][k] * W3[k * DOUT + tid];
        out[b * DOUT + tid] = o;
    }
}

// ---------------------------------------------------------------------------
extern "C" void kernel_launch(void* const* d_in, const int* in_sizes, int n_in,
                              void* d_out, int out_size, void* d_ws, size_t ws_size,
                              hipStream_t stream) {
    const float* x    = (const float*)d_in[0];
    const float* W1   = (const float*)d_in[1];
    const float* b1   = (const float*)d_in[2];
    const float* rcW1 = (const float*)d_in[3];
    const float* rcb1 = (const float*)d_in[4];
    const float* W2   = (const float*)d_in[5];
    const float* b2   = (const float*)d_in[6];
    const float* rcW2 = (const float*)d_in[7];
    const float* rcb2 = (const float*)d_in[8];
    const float* W3   = (const float*)d_in[9];
    const float* b3   = (const float*)d_in[10];

    float* out = (float*)d_out;
    float* H1  = (float*)d_ws;   // 64000 x 128 f32 = 32.77 MB

    gemm_h1<<<(Bb * Tt) / BM, 256, 0, stream>>>(x, W1, b1, H1);
    recurrent<<<Bb, 256, 0, stream>>>(H1, rcW1, rcb1, W2, b2, rcW2, rcb2, W3,
                                      b3, out);
}